// Round 7
// baseline (600.608 us; speedup 1.0000x reference)
//
#include <hip/hip_runtime.h>
#include <hip/hip_cooperative_groups.h>

namespace cg = cooperative_groups;

// RainbowEvolution T=1024 L=32 D=512 P=512 H=2048. fp32 in / fp32 out (verified R5).
// R7: ONE cooperative kernel, 11 grid.sync() phases instead of 19 launches —
// attacks the ~150 us inter-kernel dispatch overhead measured in R6.
// Grid 256x512 (1 block/CU co-resident). No atomics (deterministic).
// Scratch in d_out's aligned_prompts region (67 MB), consumed before the
// final broadcast phase overwrites it.

typedef unsigned int u32;

static constexpr int T_ = 1024, L_ = 32, D_ = 512, P_ = 512, H_ = 2048;
static constexpr float SCALE = 0.04419417382415922f; // 1/sqrt(512)
static constexpr float EPS_ = 1e-5f;

// ws offsets (fp32, ws = out + OFFO_AP)
static constexpr int OFF_QUERY   = 0;        // [32,512]
static constexpr int OFF_TV      = 16384;    // [512]
static constexpr int OFF_PQ      = 16896;    // [512]
static constexpr int OFF_WKTV    = 17408;    // [512]
static constexpr int OFF_WKPQ    = 17920;    // [512]
static constexpr int OFF_U       = 18432;    // [1024]
static constexpr int OFF_V       = 19456;    // [1024]
static constexpr int OFF_C       = 20480;    // [1024]
static constexpr int OFF_SBUF    = 21504;    // [1024,512] S[t,d]=sum_l base
static constexpr int OFF_PART    = 545792;   // [32l,8tc,512]
static constexpr int OFF_WBASE   = 676864;   // [32,512]
static constexpr int OFF_WKEY    = 693248;   // [32,512]
static constexpr int OFF_WVAL    = 709632;   // [32,512]
static constexpr int OFF_FA      = 726016;   // [32,32]
static constexpr int OFF_EVOLVED = 727040;   // [32,512]
static constexpr int OFF_H1      = 743424;   // [32,2048]
static constexpr int OFF_P2      = 808960;   // [32l,8kc,512] mlp2 partials
// ends 940032 << 16.77M floats in AP region

// out layout (fp32): aligned, aligned_prompts, task_weights, feature_attn
static constexpr int OFFO_AL = 0;
static constexpr int OFFO_AP = 16384;
static constexpr int OFFO_TW = 16384 + 16777216;   // 16793600
static constexpr int OFFO_FA = OFFO_TW + 1024;     // 16794624

struct Params {
    const float *base, *np, *te, *Wt, *bt, *Wq, *bq, *Wk, *bk, *Wv, *bv,
                *Wo, *bo, *Wa1, *ba1, *Wa2, *ba2, *g_in, *b_in, *g_out, *b_out;
    float* out;
};

__device__ __forceinline__ float wred(float v) {
    #pragma unroll
    for (int off = 32; off > 0; off >>= 1) v += __shfl_down(v, off, 64);
    return v;
}
__device__ __forceinline__ float fsum512(float v, float* buf, int tid) {
    v = wred(v);
    if ((tid & 63) == 0) buf[tid >> 6] = v;
    __syncthreads();
    if (tid == 0) { float s = 0.f; for (int i = 0; i < 8; ++i) s += buf[i]; buf[0] = s; }
    __syncthreads();
    float r = buf[0];
    __syncthreads();
    return r;
}
__device__ __forceinline__ float fmax512(float v, float* buf, int tid) {
    #pragma unroll
    for (int off = 32; off > 0; off >>= 1) v = fmaxf(v, __shfl_down(v, off, 64));
    if ((tid & 63) == 0) buf[tid >> 6] = v;
    __syncthreads();
    if (tid == 0) { float s = buf[0]; for (int i = 1; i < 8; ++i) s = fmaxf(s, buf[i]); buf[0] = s; }
    __syncthreads();
    float r = buf[0];
    __syncthreads();
    return r;
}

__global__ void __launch_bounds__(512) k_mega(Params P) {
    cg::grid_group g = cg::this_grid();
    __shared__ __align__(16) float sm[576];
    __shared__ float buf[8];
    const int b = blockIdx.x, tid = threadIdx.x;
    float* out = P.out;
    float* ws = out + OFFO_AP;

    // ---- P0: S-scan (all 256 blocks, 4 t each) + query/tv GEMM (blocks 0..32)
    for (int i = 0; i < 4; ++i) {
        int t = b + i * 256;
        const float* bp = P.base + (size_t)t * (L_ * D_) + tid;
        float s = 0.f;
        #pragma unroll
        for (int l = 0; l < L_; ++l) s += bp[l * D_];
        ws[OFF_SBUF + t * D_ + tid] = s;
    }
    if (b < 33) {
        const float* x = (b < L_) ? (P.np + b * D_) : P.te;
        const float* W = (b < L_) ? P.Wq : P.Wt;
        sm[tid] = x[tid];
        __syncthreads();
        float a0 = 0, a1 = 0, a2 = 0, a3 = 0;
        for (int d = 0; d < D_; d += 4) {
            a0 = fmaf(sm[d],     W[(size_t)(d)     * P_ + tid], a0);
            a1 = fmaf(sm[d + 1], W[(size_t)(d + 1) * P_ + tid], a1);
            a2 = fmaf(sm[d + 2], W[(size_t)(d + 2) * P_ + tid], a2);
            a3 = fmaf(sm[d + 3], W[(size_t)(d + 3) * P_ + tid], a3);
        }
        float acc = (a0 + a1) + (a2 + a3);
        if (b < L_) ws[OFF_QUERY + b * P_ + tid] = acc + P.bq[tid];
        else        ws[OFF_TV + tid] = tanhf(acc + P.bt[tid]);
    }
    g.sync();

    // ---- P1: WKTV/WKPQ (blocks 0..63, wave-per-d). PQ computed per-block (L2-hot).
    if (b < 64) {
        float s = 0.f;
        #pragma unroll
        for (int l = 0; l < L_; ++l) s += ws[OFF_QUERY + l * P_ + tid];
        s *= (1.0f / L_);
        sm[tid] = s;
        if (b == 0) ws[OFF_PQ + tid] = s;
        __syncthreads();
        int wv = tid >> 6, lane = tid & 63;
        int d = b * 8 + wv;
        const float4* row = (const float4*)(P.Wk + (size_t)d * P_);
        const float4* tv4 = (const float4*)(ws + OFF_TV);
        const float4* pq4 = (const float4*)sm;
        float4 a = row[lane * 2], c = row[lane * 2 + 1];
        float4 t0 = tv4[lane * 2], t1 = tv4[lane * 2 + 1];
        float4 q0 = pq4[lane * 2], q1 = pq4[lane * 2 + 1];
        float pa = a.x * t0.x + a.y * t0.y + a.z * t0.z + a.w * t0.w
                 + c.x * t1.x + c.y * t1.y + c.z * t1.z + c.w * t1.w;
        float pb = a.x * q0.x + a.y * q0.y + a.z * q0.z + a.w * q0.w
                 + c.x * q1.x + c.y * q1.y + c.z * q1.z + c.w * q1.w;
        pa = wred(pa); pb = wred(pb);
        if (lane == 0) { ws[OFF_WKTV + d] = pa; ws[OFF_WKPQ + d] = pb; }
    }
    g.sync();

    // ---- P2: U[t], V[t] from SBUF (all blocks, 4 t each)
    {
        float wt = ws[OFF_WKTV + tid], wq = ws[OFF_WKPQ + tid];
        for (int i = 0; i < 4; ++i) {
            int t = b * 4 + i;
            float s = ws[OFF_SBUF + t * D_ + tid];
            float up = fsum512(s * wt, buf, tid);
            float vp = fsum512(s * wq, buf, tid);
            if (tid == 0) {
                ws[OFF_U + t] = up * (1.0f / L_);
                ws[OFF_V + t] = vp * (1.0f / L_);
            }
        }
    }
    g.sync();

    // ---- P3: softmax chain (block 0) -> task_weights out + C[t]
    if (b == 0) {
        float bkt = fsum512(P.bk[tid] * ws[OFF_TV + tid], buf, tid);
        float bkq = fsum512(P.bk[tid] * ws[OFF_PQ + tid], buf, tid);

        float s1[2], e1[2], tw1[2], lmax = -1e30f;
        #pragma unroll
        for (int k = 0; k < 2; ++k) {
            s1[k] = (ws[OFF_U + tid + k * 512] + bkt) * SCALE;
            lmax = fmaxf(lmax, s1[k]);
        }
        float gmax = fmax512(lmax, buf, tid);
        float ls = 0.f;
        #pragma unroll
        for (int k = 0; k < 2; ++k) { e1[k] = expf(s1[k] - gmax); ls += e1[k]; }
        float gs = fsum512(ls, buf, tid);
        #pragma unroll
        for (int k = 0; k < 2; ++k) tw1[k] = e1[k] / gs;

        float p2[2], e2[2];
        lmax = -1e30f;
        #pragma unroll
        for (int k = 0; k < 2; ++k) {
            p2[k] = ((1.0f + tw1[k]) * ws[OFF_V + tid + k * 512] + bkq) * SCALE;
            lmax = fmaxf(lmax, p2[k]);
        }
        gmax = fmax512(lmax, buf, tid);
        ls = 0.f;
        #pragma unroll
        for (int k = 0; k < 2; ++k) { e2[k] = expf(p2[k] - gmax); ls += e2[k]; }
        gs = fsum512(ls, buf, tid);

        float tw[2], lsum = 0.f;
        #pragma unroll
        for (int k = 0; k < 2; ++k) { tw[k] = 0.5f * tw1[k] + 0.5f * (e2[k] / gs); lsum += tw[k]; }
        float S = fsum512(lsum, buf, tid);
        S = fmaxf(S, 1e-6f);
        #pragma unroll
        for (int k = 0; k < 2; ++k) {
            int t = tid + k * 512;
            float twn = tw[k] / S;
            out[OFFO_TW + t] = twn;
            ws[OFF_C + t] = twn * (1.0f + tw1[k]);
        }
    }
    g.sync();

    // ---- P4: WBASE partials (all blocks: l = b>>3, tc = b&7, 128 t each)
    {
        int l = b >> 3, tc = b & 7;
        if (tid < 128) sm[tid] = ws[OFF_C + tc * 128 + tid];
        __syncthreads();
        const float* bp = P.base + ((size_t)(tc * 128) * L_ + l) * D_ + tid;
        float acc = 0.f;
        for (int i = 0; i < 128; ++i)
            acc = fmaf(sm[i], bp[(size_t)i * (L_ * D_)], acc);
        ws[OFF_PART + (l * 8 + tc) * D_ + tid] = acc;
    }
    g.sync();

    // ---- P5: WBASE reduce + WKEY/WVAL GEMM (blocks 0..63: l = b>>1, sel = b&1)
    if (b < 64) {
        int l = b >> 1, sel = b & 1;
        float wsum = 0.f;
        #pragma unroll
        for (int tc = 0; tc < 8; ++tc) wsum += ws[OFF_PART + (l * 8 + tc) * D_ + tid];
        sm[tid] = wsum;
        if (sel == 0) ws[OFF_WBASE + l * D_ + tid] = wsum;
        __syncthreads();
        const float* W = sel ? P.Wv : P.Wk;
        float a0 = 0, a1 = 0, a2 = 0, a3 = 0;
        for (int d = 0; d < D_; d += 4) {
            a0 = fmaf(sm[d],     W[(size_t)(d)     * P_ + tid], a0);
            a1 = fmaf(sm[d + 1], W[(size_t)(d + 1) * P_ + tid], a1);
            a2 = fmaf(sm[d + 2], W[(size_t)(d + 2) * P_ + tid], a2);
            a3 = fmaf(sm[d + 3], W[(size_t)(d + 3) * P_ + tid], a3);
        }
        float acc = (a0 + a1) + (a2 + a3) + (sel ? P.bv[tid] : P.bk[tid]);
        ws[(sel ? OFF_WVAL : OFF_WKEY) + l * P_ + tid] = acc;
    }
    g.sync();

    // ---- P6: feature logits + row softmax (blocks 0..31)
    if (b < 32) {
        sm[tid] = ws[OFF_QUERY + b * P_ + tid];
        __syncthreads();
        int wv = tid >> 6, lane = tid & 63;
        const float4* sq4 = (const float4*)sm;
        float4 q0 = sq4[lane * 2], q1 = sq4[lane * 2 + 1];
        for (int gg = wv * 4; gg < wv * 4 + 4; ++gg) {
            const float4* kr = (const float4*)(ws + OFF_WKEY + (size_t)gg * P_);
            float4 a = kr[lane * 2], c = kr[lane * 2 + 1];
            float s = a.x * q0.x + a.y * q0.y + a.z * q0.z + a.w * q0.w
                    + c.x * q1.x + c.y * q1.y + c.z * q1.z + c.w * q1.w;
            s = wred(s);
            if (lane == 0) sm[512 + gg] = s * SCALE;
        }
        __syncthreads();
        if (tid < 32) {
            float mx = -1e30f;
            for (int i = 0; i < 32; ++i) mx = fmaxf(mx, sm[512 + i]);
            float S = 0.f;
            for (int i = 0; i < 32; ++i) S += expf(sm[512 + i] - mx);
            float f = expf(sm[512 + tid] - mx) / S;
            ws[OFF_FA + b * 32 + tid] = f;
            out[OFFO_FA + b * 32 + tid] = f;
        }
    }
    g.sync();

    // ---- P7: EP -> @Wo -> +WBASE+bo -> LN_in -> EVOLVED (blocks 0..31, fused)
    if (b < 32) {
        if (tid < 32) sm[512 + tid] = ws[OFF_FA + b * 32 + tid];
        __syncthreads();
        float ep = 0.f;
        #pragma unroll
        for (int j = 0; j < 32; ++j) ep = fmaf(sm[512 + j], ws[OFF_WVAL + j * P_ + tid], ep);
        __syncthreads();
        sm[tid] = ep;
        __syncthreads();
        float a0 = 0, a1 = 0, a2 = 0, a3 = 0;
        for (int p = 0; p < P_; p += 4) {
            a0 = fmaf(sm[p],     P.Wo[(size_t)(p)     * D_ + tid], a0);
            a1 = fmaf(sm[p + 1], P.Wo[(size_t)(p + 1) * D_ + tid], a1);
            a2 = fmaf(sm[p + 2], P.Wo[(size_t)(p + 2) * D_ + tid], a2);
            a3 = fmaf(sm[p + 3], P.Wo[(size_t)(p + 3) * D_ + tid], a3);
        }
        float x = ws[OFF_WBASE + b * D_ + tid] + (a0 + a1) + (a2 + a3) + P.bo[tid];
        float mean = fsum512(x, buf, tid) * (1.0f / D_);
        float dx = x - mean;
        float var = fsum512(dx * dx, buf, tid) * (1.0f / D_);
        ws[OFF_EVOLVED + b * D_ + tid] = dx * rsqrtf(var + EPS_) * P.g_in[tid] + P.b_in[tid];
    }
    g.sync();

    // ---- P8: mlp1 (blocks 0..127: l = b>>2, hc = b&3)
    if (b < 128) {
        int l = b >> 2, hc = b & 3;
        sm[tid] = ws[OFF_EVOLVED + l * D_ + tid];
        __syncthreads();
        int h = hc * 512 + tid;
        float a0 = 0, a1 = 0, a2 = 0, a3 = 0;
        for (int d = 0; d < D_; d += 4) {
            a0 = fmaf(sm[d],     P.Wa1[(size_t)(d)     * H_ + h], a0);
            a1 = fmaf(sm[d + 1], P.Wa1[(size_t)(d + 1) * H_ + h], a1);
            a2 = fmaf(sm[d + 2], P.Wa1[(size_t)(d + 2) * H_ + h], a2);
            a3 = fmaf(sm[d + 3], P.Wa1[(size_t)(d + 3) * H_ + h], a3);
        }
        ws[OFF_H1 + l * H_ + h] = fmaxf((a0 + a1) + (a2 + a3) + P.ba1[h], 0.f);
    }
    g.sync();

    // ---- P9: mlp2 split-K partials (all blocks: l = b>>3, kc = b&7)
    {
        int l = b >> 3, kc = b & 7;
        if (tid < 256) sm[tid] = ws[OFF_H1 + l * H_ + kc * 256 + tid];
        __syncthreads();
        float a0 = 0, a1 = 0, a2 = 0, a3 = 0;
        for (int j = 0; j < 256; j += 4) {
            a0 = fmaf(sm[j],     P.Wa2[(size_t)(kc * 256 + j)     * D_ + tid], a0);
            a1 = fmaf(sm[j + 1], P.Wa2[(size_t)(kc * 256 + j + 1) * D_ + tid], a1);
            a2 = fmaf(sm[j + 2], P.Wa2[(size_t)(kc * 256 + j + 2) * D_ + tid], a2);
            a3 = fmaf(sm[j + 3], P.Wa2[(size_t)(kc * 256 + j + 3) * D_ + tid], a3);
        }
        ws[OFF_P2 + (l * 8 + kc) * D_ + tid] = (a0 + a1) + (a2 + a3);
    }
    g.sync();

    // ---- P10: aligned = LN(EVOLVED + sum partials + ba2) (blocks 0..31)
    if (b < 32) {
        float x = ws[OFF_EVOLVED + b * D_ + tid] + P.ba2[tid];
        #pragma unroll
        for (int kc = 0; kc < 8; ++kc) x += ws[OFF_P2 + (b * 8 + kc) * D_ + tid];
        float mean = fsum512(x, buf, tid) * (1.0f / D_);
        float dx = x - mean;
        float var = fsum512(dx * dx, buf, tid) * (1.0f / D_);
        out[OFFO_AL + b * D_ + tid] = dx * rsqrtf(var + EPS_) * P.g_out[tid] + P.b_out[tid];
    }
    g.sync();

    // ---- P11: aligned_prompts broadcast (all blocks, 64 MB float4 write)
    {
        const float4* src = (const float4*)out;        // 4096 float4 = aligned
        float4* dst = (float4*)(out + OFFO_AP);
        int gt = b * 512 + tid;                        // 0..131071
        #pragma unroll
        for (int k = 0; k < 32; ++k) {
            int v = gt + k * 131072;                   // 4194304 total
            dst[v] = src[v & 4095];
        }
    }
}

extern "C" void kernel_launch(void* const* d_in, const int* in_sizes, int n_in,
                              void* d_out, int out_size, void* d_ws, size_t ws_size,
                              hipStream_t stream) {
    Params Pm;
    Pm.base = (const float*)d_in[0];
    Pm.np   = (const float*)d_in[1];
    Pm.te   = (const float*)d_in[2];
    Pm.Wt   = (const float*)d_in[3];
    Pm.bt   = (const float*)d_in[4];
    Pm.Wq   = (const float*)d_in[5];
    Pm.bq   = (const float*)d_in[6];
    Pm.Wk   = (const float*)d_in[7];
    Pm.bk   = (const float*)d_in[8];
    Pm.Wv   = (const float*)d_in[9];
    Pm.bv   = (const float*)d_in[10];
    Pm.Wo   = (const float*)d_in[11];
    Pm.bo   = (const float*)d_in[12];
    Pm.Wa1  = (const float*)d_in[13];
    Pm.ba1  = (const float*)d_in[14];
    Pm.Wa2  = (const float*)d_in[15];
    Pm.ba2  = (const float*)d_in[16];
    Pm.g_in = (const float*)d_in[17];
    Pm.b_in = (const float*)d_in[18];
    Pm.g_out= (const float*)d_in[19];
    Pm.b_out= (const float*)d_in[20];
    Pm.out  = (float*)d_out;

    void* args[] = { &Pm };
    hipLaunchCooperativeKernel((const void*)k_mega, dim3(256), dim3(512), args, 0, stream);
}